// Round 13
// baseline (186.288 us; speedup 1.0000x reference)
//
#include <hip/hip_runtime.h>

#define HH 299
#define WW 299
#define HW (HH * WW)
#define BORDER 3
#define NT 320
#define RPB 4
#define CHUNKS 75            // ceil(299/4)
#define INV299 (1.0f / 299.0f)

typedef float f4 __attribute__((ext_vector_type(4)));
typedef f4 __attribute__((aligned(4)))  f4a;    // 4B-aligned float4 load
typedef f4 __attribute__((aligned(16))) f4al;   // 16B-aligned float4 store

__global__ __launch_bounds__(NT) void crop_resize_kernel(
    const float* __restrict__ x,   // (S, 3, H, W)
    const int*   __restrict__ f,   // (S, G, 4)
    float*       __restrict__ out, // (S, G, 3, H, W)
    int G)
{
    __shared__ float sV[RPB][3][304];   // fused vertical rows, 14.6 KB

    // Bijective XCD swizzle (grid = 38400 = 8 * 4800).
    int cpx = (int)(gridDim.x >> 3);
    int hb  = blockIdx.x;
    int blk = (hb & 7) * cpx + (hb >> 3);

    int sg = blk / CHUNKS;               // crop index si*G + gi
    int r0 = (blk - sg * CHUNKS) * RPB;  // first output row of this block
    int si = sg / G;

    const int* box = f + (sg << 2);
    int tlx = max(box[0] - BORDER, 0);
    int tly = max(box[1] - BORDER, 0);
    int hc  = min(box[2] + BORDER, HH - 1) - tlx;
    int wc  = min(box[3] + BORDER, WW - 1) - tly;

    int t = threadIdx.x;
    const float* img = x + si * 3 * HW;

    // Row (x-axis) coords for RPB rows — block-uniform, division-free.
    float hstep = (float)hc * INV299;
    int   gxb[RPB]; float fxa[RPB];
    #pragma unroll
    for (int r = 0; r < RPB; ++r) {
        int row = min(r0 + r, HH - 1);
        float sx = fmaf((float)row + 0.5f, hstep, -0.5f);
        sx = fminf(fmaxf(sx, 0.0f), (float)hc - 1.0f);
        int bx = max(min((int)floorf(sx), hc - 2), 0);
        fxa[r] = sx - (float)bx;
        gxb[r] = tlx + bx;
    }

    // Staging (identical to R10): unit u -> (r, ch, quad).
    #pragma unroll
    for (int pass = 0; pass < 3; ++pass) {
        int u = t + pass * NT;
        if (u < RPB * 228) {
            int r  = u / 228;
            int m  = u - r * 228;
            int ch = m / 76;
            int q  = (m - ch * 76) << 2;
            if (q < wc) {
                int c = min(q, wc - 3);          // 16B read stays inside row
                const float* p = img + ch * HW + gxb[r] * WW + tly + c;
                f4 a = *(const f4a*)p;           // source row bx
                f4 b = *(const f4a*)(p + WW);    // source row bx+1
                float fr = fxa[r], om = 1.0f - fr;
                sV[r][ch][c + 0] = fmaf(a.x, om, b.x * fr);
                sV[r][ch][c + 1] = fmaf(a.y, om, b.y * fr);
                sV[r][ch][c + 2] = fmaf(a.z, om, b.z * fr);
                sV[r][ch][c + 3] = fmaf(a.w, om, b.w * fr);
            }
        }
    }
    __syncthreads();

    // ---- Output: fixed column-quad per thread, ALIGNED dwordx4 stores ----
    if (t >= 304) return;
    int r = t / 76;                  // 0..3  (mild intra-wave split, 2 cases)
    int q = t - r * 76;              // 0..75
    int row = r0 + r;
    if (row >= HH) return;           // tail chunk guard

    // 8 coord pairs for cols (4q-4 .. 4q+3) — named registers, computed once.
    float wstep = (float)wc * INV299;
    int qb = (q << 2) - 4;
    int   by0, by1, by2, by3, by4, by5, by6, by7;
    float fy0, fy1, fy2, fy3, fy4, fy5, fy6, fy7;
    #define MKCOORD(K, BY, FY) do {                                        \
        int col = qb + K; col = col < 0 ? 0 : (col > 298 ? 298 : col);     \
        float sy = fmaf((float)col + 0.5f, wstep, -0.5f);                  \
        sy = fminf(fmaxf(sy, 0.0f), (float)wc - 1.0f);                     \
        int b = (int)floorf(sy);                                           \
        b = b > wc - 2 ? wc - 2 : b; b = b < 0 ? 0 : b;                    \
        BY = b; FY = sy - (float)b; } while (0)
    MKCOORD(0, by0, fy0); MKCOORD(1, by1, fy1);
    MKCOORD(2, by2, fy2); MKCOORD(3, by3, fy3);
    MKCOORD(4, by4, fy4); MKCOORD(5, by5, fy5);
    MKCOORD(6, by6, fy6); MKCOORD(7, by7, fy7);
    #undef MKCOORD

    #define PAIR(B, F) fmaf(v[B], 1.0f - (F), v[(B) + 1] * (F))
    #define CASEBODY(bA,fA,bB,fB,bC,fC,bD,fD)  \
        o.x = PAIR(bA, fA); o.y = PAIR(bB, fB); \
        o.z = PAIR(bC, fC); o.w = PAIR(bD, fD);

    #pragma unroll
    for (int ch = 0; ch < 3; ++ch) {
        int base = (sg * 3 + ch) * HW + row * WW;   // element index (<2^31)
        int phase = base & 3;                       // store alignment phase
        const float* v = &sV[r][ch][0];
        f4 o; int c0;
        switch (phase) {                            // uniform per (r,ch)
        case 0:  c0 = (q << 2);     CASEBODY(by4,fy4,by5,fy5,by6,fy6,by7,fy7); break;
        case 1:  c0 = (q << 2) - 1; CASEBODY(by3,fy3,by4,fy4,by5,fy5,by6,fy6); break;
        case 2:  c0 = (q << 2) - 2; CASEBODY(by2,fy2,by3,fy3,by4,fy4,by5,fy5); break;
        default: c0 = (q << 2) - 3; CASEBODY(by1,fy1,by2,fy2,by3,fy3,by4,fy4); break;
        }
        if (c0 >= 0 && c0 <= WW - 4) {
            *(f4al*)(out + base + c0) = o;          // aligned dwordx4
        } else {                                    // row head/tail lanes only
            if (c0     >= 0 && c0     < WW) out[base + c0]     = o.x;
            if (c0 + 1 >= 0 && c0 + 1 < WW) out[base + c0 + 1] = o.y;
            if (c0 + 2 >= 0 && c0 + 2 < WW) out[base + c0 + 2] = o.z;
            if (c0 + 3 >= 0 && c0 + 3 < WW) out[base + c0 + 3] = o.w;
        }
    }
    #undef PAIR
    #undef CASEBODY
}

extern "C" void kernel_launch(void* const* d_in, const int* in_sizes, int n_in,
                              void* d_out, int out_size, void* d_ws, size_t ws_size,
                              hipStream_t stream) {
    const float* x = (const float*)d_in[0];
    const int*   f = (const int*)d_in[1];
    float* out = (float*)d_out;

    int S = in_sizes[0] / (3 * HW);   // 32
    int G = in_sizes[1] / (S * 4);    // 16

    dim3 grid((unsigned)(S * G * CHUNKS));  // 38400 = 8 * 4800
    dim3 block(NT);
    crop_resize_kernel<<<grid, block, 0, stream>>>(x, f, out, G);
}

// Round 14
// 152.305 us; speedup vs baseline: 1.2231x; 1.2231x over previous
//
#include <hip/hip_runtime.h>

#define HH 299
#define WW 299
#define HW (HH * WW)
#define BORDER 3
#define NT 256
#define RPB 4
#define CHUNKS 75            // ceil(299/4)
#define INV299 (1.0f / 299.0f)

typedef float f4 __attribute__((ext_vector_type(4)));
typedef f4 __attribute__((aligned(4))) f4a;   // 4B-aligned float4 loads

__global__ __launch_bounds__(NT) void crop_resize_kernel(
    const float* __restrict__ x,   // (S, 3, H, W)
    const int*   __restrict__ f,   // (S, G, 4)
    float*       __restrict__ out, // (S, G, 3, H, W)
    int G)
{
    __shared__ float sV[RPB][3][304];   // fused vertical rows, 14.6 KB

    // Bijective XCD swizzle (grid = 38400 = 8 * 4800): contiguous logical
    // chunks per XCD -> a crop's blocks (and its image) stay in one L2.
    int cpx = (int)(gridDim.x >> 3);
    int hb  = blockIdx.x;
    int blk = (hb & 7) * cpx + (hb >> 3);

    int sg = blk / CHUNKS;               // crop index si*G + gi
    int r0 = (blk - sg * CHUNKS) * RPB;  // first output row of this block
    int si = sg / G;

    const int* box = f + (sg << 2);
    int tlx = max(box[0] - BORDER, 0);
    int tly = max(box[1] - BORDER, 0);
    int hc  = min(box[2] + BORDER, HH - 1) - tlx;
    int wc  = min(box[3] + BORDER, WW - 1) - tly;

    int t = threadIdx.x;
    const float* img = x + si * 3 * HW;

    // Row (x-axis) coords for RPB rows — block-uniform, division-free.
    float hstep = (float)hc * INV299;
    int   gxb[RPB]; float fxa[RPB];
    #pragma unroll
    for (int r = 0; r < RPB; ++r) {
        int row = min(r0 + r, HH - 1);           // tail dup is harmless
        float sx = fmaf((float)row + 0.5f, hstep, -0.5f);
        sx = fminf(fmaxf(sx, 0.0f), (float)hc - 1.0f);
        int bx = max(min((int)floorf(sx), hc - 2), 0);
        fxa[r] = sx - (float)bx;
        gxb[r] = tlx + bx;
    }

    // Staging: unit u in [0, RPB*228): r = u/228, ch = (u%228)/76, quad q.
    // 912 units over 256 threads -> 4 passes, all loads independent.
    #pragma unroll
    for (int pass = 0; pass < 4; ++pass) {
        int u = t + pass * NT;
        if (u < RPB * 228) {
            int r  = u / 228;
            int m  = u - r * 228;
            int ch = m / 76;
            int q  = (m - ch * 76) << 2;
            if (q < wc) {
                int c = min(q, wc - 3);          // 16B read stays inside row
                const float* p = img + ch * HW + gxb[r] * WW + tly + c;
                f4 a = *(const f4a*)p;           // source row bx
                f4 b = *(const f4a*)(p + WW);    // source row bx+1
                float fr = fxa[r], om = 1.0f - fr;
                sV[r][ch][c + 0] = fmaf(a.x, om, b.x * fr);
                sV[r][ch][c + 1] = fmaf(a.y, om, b.y * fr);
                sV[r][ch][c + 2] = fmaf(a.z, om, b.z * fr);
                sV[r][ch][c + 3] = fmaf(a.w, om, b.w * fr);
            }
        }
    }
    __syncthreads();

    // Output: col j per thread (2 passes: 256 + ragged 43).
    for (int j = t; j < WW; j += NT) {
        float sy = fmaf((float)j + 0.5f, (float)wc * INV299, -0.5f);
        sy = fminf(fmaxf(sy, 0.0f), (float)wc - 1.0f);
        int by = max(min((int)floorf(sy), wc - 2), 0);
        float fy   = sy - (float)by;
        float omfy = 1.0f - fy;

        #pragma unroll
        for (int r = 0; r < RPB; ++r) {
            int row = r0 + r;
            if (row < HH) {                      // uniform guard (tail block)
                int obase = (sg * 3 * HH + row) * WW + j;
                #pragma unroll
                for (int ch = 0; ch < 3; ++ch) {
                    out[obase + ch * HW] =
                        fmaf(sV[r][ch][by], omfy, sV[r][ch][by + 1] * fy);
                }
            }
        }
    }
}

extern "C" void kernel_launch(void* const* d_in, const int* in_sizes, int n_in,
                              void* d_out, int out_size, void* d_ws, size_t ws_size,
                              hipStream_t stream) {
    const float* x = (const float*)d_in[0];
    const int*   f = (const int*)d_in[1];
    float* out = (float*)d_out;

    int S = in_sizes[0] / (3 * HW);   // 32
    int G = in_sizes[1] / (S * 4);    // 16

    dim3 grid((unsigned)(S * G * CHUNKS));  // 38400 = 8 * 4800
    dim3 block(NT);
    crop_resize_kernel<<<grid, block, 0, stream>>>(x, f, out, G);
}